// Round 5
// baseline (392.833 us; speedup 1.0000x reference)
//
#include <hip/hip_runtime.h>

// Aggregate = column segment-sum: out[b][g] = sum_{c: sid[c]==g} x[b][c]
// x: [8192, 8192] f32, sid: [8192] i32 in [0,512), out: [8192, 512] f32.
//
// R1: LDS atomic scatter = lane-serial atomic unit, 341us, all pipes idle.
// R2: CSR gather, 167us. Counters: FETCH 194MB + WRITE 257MB phantom = 451MB.
// R3: row pairs + nontemporal + 1 barrier/row, 2 blocks/CU: k_main ~90us.
// R4: single-row @ 3 blocks/CU REGRESSED (+20us): barrier rate doubled;
//     occupancy was not the constraint. LDS pipe only ~20% busy.
// R5: the 257MB phantom write = harness-dirtied L3 lines evicted by our
//     x-stream (real HBM traffic -> inflated floor 72us). Attack both:
//     (a) global_load_lds DMA staging with aux=NT|SC1 streaming policy to
//         avoid L3 allocation (kills the writeback if the bits take);
//     (b) double-buffered async: issue row r+1 DMA, gather row r, ONE
//         __syncthreads per row whose vmcnt drain waits on loads issued a
//         full gather-phase earlier. No register round-trip.
// LDS: y[2][8192] f32 (64KB) + col16[8192] u16 (16KB) = 80KB -> 2 blocks/CU.

#define NCLS 8192
#define NGRP 512
#define ROWS 16
#define TPB  256
#define AUX  0x12  // NT(0x2) | SC1(0x10): streaming / far-cache-bypass hint

typedef float vf2 __attribute__((ext_vector_type(2)));
typedef const __attribute__((address_space(1))) void* gp_t;
typedef __attribute__((address_space(3))) void* lp_t;

// d_ws layout (ints): hist[512] @0, offs[513] @512, curs[512] @1088, cols[8192] @1600

__global__ __launch_bounds__(512) void k_hist(const int* __restrict__ sid,
                                              int* __restrict__ hist) {
    int i = blockIdx.x * 512 + threadIdx.x;
    atomicAdd(&hist[sid[i]], 1);
}

__global__ __launch_bounds__(512) void k_scan(const int* __restrict__ hist,
                                              int* __restrict__ offs,
                                              int* __restrict__ curs) {
    __shared__ int tmp[NGRP];
    const int t = threadIdx.x;
    const int h = hist[t];
    tmp[t] = h;
    __syncthreads();
    for (int off = 1; off < NGRP; off <<= 1) {
        int v = tmp[t];
        int u = (t >= off) ? tmp[t - off] : 0;
        __syncthreads();
        tmp[t] = v + u;
        __syncthreads();
    }
    int excl = tmp[t] - h;   // exclusive prefix sum
    offs[t] = excl;
    curs[t] = excl;
    if (t == NGRP - 1) offs[NGRP] = NCLS;
}

__global__ __launch_bounds__(512) void k_scatter(const int* __restrict__ sid,
                                                 int* __restrict__ curs,
                                                 int* __restrict__ cols) {
    int c = blockIdx.x * 512 + threadIdx.x;
    int g = sid[c];
    int pos = atomicAdd(&curs[g], 1);  // order within group irrelevant (sum)
    cols[pos] = c;
}

__global__ __launch_bounds__(TPB) void k_main(const float* __restrict__ x,
                                              const int* __restrict__ cols,
                                              const int* __restrict__ offs,
                                              float* __restrict__ out) {
    __shared__ float y[2][NCLS];             // 64 KB: double-buffered row
    __shared__ unsigned short col16[NCLS];   // 16 KB: CSR column ids (u16)
    const int tid  = threadIdx.x;
    const int row0 = blockIdx.x * ROWS;

    // Cache CSR column list in LDS (u16), vectorized.
    for (int i = tid; i < NCLS / 4; i += TPB) {
        int4 c = reinterpret_cast<const int4*>(cols)[i];
        ushort4 u;
        u.x = (unsigned short)c.x; u.y = (unsigned short)c.y;
        u.z = (unsigned short)c.z; u.w = (unsigned short)c.w;
        *reinterpret_cast<ushort4*>(&col16[4 * i]) = u;
    }

    // Thread owns groups 2*tid and 2*tid+1.
    const int s0 = offs[2 * tid];
    const int e0 = offs[2 * tid + 1];
    const int e1 = offs[2 * tid + 2];

    // Async DMA row 0 -> y[0]. LDS dest is wave-uniform base + lane*16:
    // byte addr = 4096*k + 1024*wave + 16*lane  (tid*4 floats = tid*16 bytes).
    {
        const float* xr = x + (size_t)row0 * NCLS;
#pragma unroll
        for (int k = 0; k < 8; ++k)
            __builtin_amdgcn_global_load_lds((gp_t)(xr + k * 1024 + tid * 4),
                                             (lp_t)(&y[0][k * 1024 + tid * 4]),
                                             16, 0, AUX);
    }
    __syncthreads();  // vmcnt drain: row 0 resident; col16 published

    for (int r = 0; r < ROWS; ++r) {
        const int cur = r & 1;
        const int nxt = cur ^ 1;

        // Issue next row's DMA first (fully async; consumed at next barrier).
        if (r + 1 < ROWS) {
            const float* xr = x + (size_t)(row0 + r + 1) * NCLS;
#pragma unroll
            for (int k = 0; k < 8; ++k)
                __builtin_amdgcn_global_load_lds(
                    (gp_t)(xr + k * 1024 + tid * 4),
                    (lp_t)(&y[nxt][k * 1024 + tid * 4]), 16, 0, AUX);
        }

        // Gather this row's two group-sums from the resident buffer.
        const float* yr = y[cur];
        float sum0 = 0.f, sum1 = 0.f;
        for (int p = s0; p < e0; ++p) sum0 += yr[col16[p]];
        for (int p = e0; p < e1; ++p) sum1 += yr[col16[p]];

        {
            vf2 o; o.x = sum0; o.y = sum1;
            __builtin_nontemporal_store(
                o, reinterpret_cast<vf2*>(out + (size_t)(row0 + r) * NGRP + 2 * tid));
        }

        // One barrier per row: publishes y[nxt] (vmcnt drain covers DMA issued
        // a full gather-phase ago) and guards y[cur] reuse next iteration.
        __syncthreads();
    }
}

extern "C" void kernel_launch(void* const* d_in, const int* in_sizes, int n_in,
                              void* d_out, int out_size, void* d_ws, size_t ws_size,
                              hipStream_t stream) {
    const float* x   = (const float*)d_in[0];
    const int*   sid = (const int*)d_in[1];
    float*       out = (float*)d_out;

    int* ws   = (int*)d_ws;
    int* hist = ws;
    int* offs = ws + 512;
    int* curs = ws + 1088;
    int* cols = ws + 1600;

    const int batch  = in_sizes[0] / NCLS;   // 8192
    const int blocks = batch / ROWS;         // 512

    hipMemsetAsync(hist, 0, NGRP * sizeof(int), stream);
    k_hist<<<NCLS / 512, 512, 0, stream>>>(sid, hist);
    k_scan<<<1, NGRP, 0, stream>>>(hist, offs, curs);
    k_scatter<<<NCLS / 512, 512, 0, stream>>>(sid, curs, cols);
    k_main<<<blocks, TPB, 0, stream>>>(x, cols, offs, out);
}